// Round 7
// baseline (421.756 us; speedup 1.0000x reference)
//
#include <hip/hip_runtime.h>
#include <hip/hip_bf16.h>

constexpr int F_IN  = 512;
constexpr int HID   = 16;
constexpr int NCLS  = 40;
constexpr int CHUNK = 4096;   // edges per count/scatter block
constexpr int BMAX  = 800;    // max buckets (N=100000 -> NB=782)
constexpr int SMAX  = 6144;   // max edges per bucket (mean 4096, sd 64 -> 32 sigma)
constexpr int GR    = 64;     // gemm1 rows per block
constexpr int GKC   = 64;     // gemm1 k-chunk

// ---- Pass A: per-chunk histogram of dst buckets (LDS atomics only) ----
__global__ void k_count(const int* __restrict__ dst, int* __restrict__ counts,
                        int E, int NB, int NBLKp) {
  __shared__ int hist[BMAX];
  int t = threadIdx.x;
  for (int b = t; b < BMAX; b += 256) hist[b] = 0;
  __syncthreads();
  int base = blockIdx.x * CHUNK;
  for (int i = 0; i < CHUNK; i += 256) {
    int e = base + i + t;
    if (e < E) atomicAdd(&hist[dst[e] >> 7], 1);
  }
  __syncthreads();
  for (int b = t; b < NB; b += 256) counts[b * NBLKp + blockIdx.x] = hist[b];
}

// ---- scan over counts (bucket-major), 3 stages, in-place ----
__global__ void k_scanA(const int* __restrict__ a, int* __restrict__ bsum) {
  __shared__ int sd[256];
  int t = threadIdx.x;
  int4 v = reinterpret_cast<const int4*>(a)[blockIdx.x * 256 + t];
  sd[t] = v.x + v.y + v.z + v.w;
  __syncthreads();
  for (int off = 128; off > 0; off >>= 1) {
    if (t < off) sd[t] += sd[t + off];
    __syncthreads();
  }
  if (!t) bsum[blockIdx.x] = sd[0];
}

__global__ void k_scanB(int* __restrict__ bsum, int nb) {
  __shared__ int sd[1024];
  int t = threadIdx.x;
  int v = (t < nb) ? bsum[t] : 0;
  sd[t] = v;
  __syncthreads();
  for (int off = 1; off < 1024; off <<= 1) {
    int add = (t >= off) ? sd[t - off] : 0;
    __syncthreads();
    sd[t] += add;
    __syncthreads();
  }
  if (t < nb) bsum[t] = sd[t] - v;  // exclusive
}

__global__ void k_scanC(int* __restrict__ a, const int* __restrict__ bsum) {
  __shared__ int sd[256];
  int t = threadIdx.x;
  int4 v = reinterpret_cast<int4*>(a)[blockIdx.x * 256 + t];
  int ts = v.x + v.y + v.z + v.w;
  sd[t] = ts;
  __syncthreads();
  for (int off = 1; off < 256; off <<= 1) {
    int add = (t >= off) ? sd[t - off] : 0;
    __syncthreads();
    sd[t] += add;
    __syncthreads();
  }
  int pre = bsum[blockIdx.x] + sd[t] - ts;
  int4 w;
  w.x = pre; w.y = pre + v.x; w.z = w.y + v.y; w.w = w.z + v.z;
  reinterpret_cast<int4*>(a)[blockIdx.x * 256 + t] = w;
}

// ---- Pass B: scatter edges into bucket-sorted payload (LDS cursors only) ----
__global__ void k_scatter(const int* __restrict__ src, const int* __restrict__ dst,
                          const float* __restrict__ ew, const int* __restrict__ counts,
                          uint2* __restrict__ payload, int E, int NB, int NBLKp) {
  __shared__ int cur[BMAX];
  int t = threadIdx.x;
  for (int b = t; b < NB; b += 256) cur[b] = counts[b * NBLKp + blockIdx.x];
  __syncthreads();
  int base = blockIdx.x * CHUNK;
  for (int i = 0; i < CHUNK; i += 256) {
    int e = base + i + t;
    if (e < E) {
      int s = src[e], d = dst[e];
      float w = ew[e];
      int pos = atomicAdd(&cur[d >> 7], 1);
      payload[pos] = make_uint2(((unsigned)s << 7) | (unsigned)(d & 127),
                                __float_as_uint(w));
    }
  }
}

// ---- Pass C: per-bucket in-place counting sort by dst-low-7 -> per-node CSR.
//      Also computes deg/dis (folds old k_degb). LDS only; no global atomics. ----
__global__ void __launch_bounds__(256)
k_sortb(uint2* __restrict__ payload, const int* __restrict__ counts,
        int* __restrict__ rs, float* __restrict__ dis, int N, int NBLKp) {
  __shared__ uint2 ebuf[SMAX];
  __shared__ int hcnt[128];
  __shared__ int sc[128];
  __shared__ float dgs[128];
  int t = threadIdx.x;
  if (t < 128) { hcnt[t] = 0; dgs[t] = 1.0f; }
  __syncthreads();
  int beg = counts[blockIdx.x * NBLKp];
  int end = counts[(blockIdx.x + 1) * NBLKp];
  int sz = end - beg;
  for (int i = t; i < sz; i += 256) {
    uint2 p = payload[beg + i];
    ebuf[i] = p;
    atomicAdd(&hcnt[p.x & 127], 1);
    atomicAdd(&dgs[p.x & 127], __uint_as_float(p.y));
  }
  __syncthreads();
  int v = (t < 128) ? hcnt[t] : 0;
  if (t < 128) sc[t] = v;
  __syncthreads();
  for (int off = 1; off < 128; off <<= 1) {
    int add = (t < 128 && t >= off) ? sc[t - off] : 0;
    __syncthreads();
    if (t < 128) sc[t] += add;
    __syncthreads();
  }
  int base = blockIdx.x * 128;
  if (t < 128) {
    int st = sc[t] - v;        // exclusive prefix within bucket
    hcnt[t] = st;              // reuse as relative cursor
    rs[base + t] = beg + st;
    int n = base + t;
    if (n < N) dis[n] = rsqrtf(dgs[t]);
  }
  if (t == 0) rs[base + 128] = end;  // overlaps next bucket's start write: same value
  __syncthreads();
  for (int i = t; i < sz; i += 256) {
    uint2 p = ebuf[i];
    int pos = beg + atomicAdd(&hcnt[p.x & 127], 1);
    payload[pos] = make_uint2(p.x >> 7, p.y);   // store plain src index + weight
  }
}

__device__ __forceinline__ float blo(unsigned u) { return __uint_as_float(u << 16); }
__device__ __forceinline__ float bhi(unsigned u) { return __uint_as_float(u & 0xffff0000u); }
__device__ __forceinline__ unsigned pack2(float lo, float hi) {
  __hip_bfloat16 l = __float2bfloat16(lo), h = __float2bfloat16(hi);
  unsigned short ul = *reinterpret_cast<unsigned short*>(&l);
  unsigned short uh = *reinterpret_cast<unsigned short*>(&h);
  return (unsigned)ul | ((unsigned)uh << 16);
}

// ---- h1' = (x @ W1) * dis[n], stored as bf16 rows (32B).
//      Tile-staged: 64 rows/block, K-chunks of 64 staged coalesced into LDS
//      (transposed xt[k][row+1]); K split 4-ways across waves (W1 stays
//      wave-uniform -> s_load); combine through LDS. ----
__global__ void __launch_bounds__(256)
k_gemm1(const float* __restrict__ x, const float* __restrict__ W1,
        const float* __restrict__ dis, uint4* __restrict__ hb1, int N) {
  __shared__ float sm[GKC * (GR + 1)];   // xt[kk][r]; reused as ps[r][64] at end
  int t = threadIdx.x;
  int r = t & 63;        // row within tile
  int s = t >> 6;        // k-slice == wave id (0..3)
  int base = blockIdx.x * GR;
  float acc[HID];
#pragma unroll
  for (int j = 0; j < HID; ++j) acc[j] = 0.0f;

  for (int c = 0; c < F_IN / GKC; ++c) {   // 8 chunks
    __syncthreads();                        // previous chunk's readers done
#pragma unroll
    for (int i = 0; i < 4; ++i) {
      int f = t + 256 * i;                  // 0..1023 float4s
      int rr = f >> 4;                      // 16 float4 per row
      int off = f & 15;
      int n = base + rr;
      if (n < N) {
        float4 v = *reinterpret_cast<const float4*>(x + (size_t)n * F_IN + c * GKC + off * 4);
        int kk = off * 4;
        sm[(kk + 0) * (GR + 1) + rr] = v.x;
        sm[(kk + 1) * (GR + 1) + rr] = v.y;
        sm[(kk + 2) * (GR + 1) + rr] = v.z;
        sm[(kk + 3) * (GR + 1) + rr] = v.w;
      }
    }
    __syncthreads();
    const float* wbase = W1 + (size_t)(c * GKC + s * 16) * HID;
#pragma unroll
    for (int kk = 0; kk < 16; ++kk) {
      float xv = sm[(s * 16 + kk) * (GR + 1) + r];
      const float* wr = wbase + kk * HID;
#pragma unroll
      for (int j = 0; j < HID; ++j) acc[j] = fmaf(xv, wr[j], acc[j]);
    }
  }
  __syncthreads();
#pragma unroll
  for (int j = 0; j < HID; ++j) sm[r * 64 + s * 16 + j] = acc[j];
  __syncthreads();
  if (t < GR) {
    int n = base + t;
    if (n < N) {
      float di = dis[n];
      float o[HID];
#pragma unroll
      for (int j = 0; j < HID; ++j)
        o[j] = (sm[t * 64 + j] + sm[t * 64 + 16 + j] +
                sm[t * 64 + 32 + j] + sm[t * 64 + 48 + j]) * di;
      uint4 w0, w1;
      w0.x = pack2(o[0],  o[1]);  w0.y = pack2(o[2],  o[3]);
      w0.z = pack2(o[4],  o[5]);  w0.w = pack2(o[6],  o[7]);
      w1.x = pack2(o[8],  o[9]);  w1.y = pack2(o[10], o[11]);
      w1.z = pack2(o[12], o[13]); w1.w = pack2(o[14], o[15]);
      hb1[(size_t)n * 2]     = w0;
      hb1[(size_t)n * 2 + 1] = w1;
    }
  }
}

// ---- aggregation: ONE NODE PER LANE, 16 f32 register accumulators, zero LDS.
//      LAYER1: hb2 = bf16( relu((acc+self)*dis+b1)*dis )   LAYER2: g = (acc+self)*dis ----
template <int LAYER>
__global__ void __launch_bounds__(256)
k_aggn(const uint2* __restrict__ payload, const int* __restrict__ rs,
       const uint4* __restrict__ hb, const float* __restrict__ dis,
       const float* __restrict__ b1, uint4* __restrict__ hb2,
       float* __restrict__ g, int N) {
  int n = blockIdx.x * 256 + threadIdx.x;
  if (n >= N) return;
  int e0 = rs[n], e1 = rs[n + 1];
  float a0 = 0, a1 = 0, a2 = 0, a3 = 0, a4 = 0, a5 = 0, a6 = 0, a7 = 0;
  float a8 = 0, a9 = 0, a10 = 0, a11 = 0, a12 = 0, a13 = 0, a14 = 0, a15 = 0;
#pragma unroll 2
  for (int e = e0; e < e1; ++e) {
    uint2 p = payload[e];
    const uint4* row = hb + ((size_t)p.x * 2);
    uint4 r0 = row[0];
    uint4 r1 = row[1];
    float w = __uint_as_float(p.y);
    a0  = fmaf(blo(r0.x), w, a0);  a1  = fmaf(bhi(r0.x), w, a1);
    a2  = fmaf(blo(r0.y), w, a2);  a3  = fmaf(bhi(r0.y), w, a3);
    a4  = fmaf(blo(r0.z), w, a4);  a5  = fmaf(bhi(r0.z), w, a5);
    a6  = fmaf(blo(r0.w), w, a6);  a7  = fmaf(bhi(r0.w), w, a7);
    a8  = fmaf(blo(r1.x), w, a8);  a9  = fmaf(bhi(r1.x), w, a9);
    a10 = fmaf(blo(r1.y), w, a10); a11 = fmaf(bhi(r1.y), w, a11);
    a12 = fmaf(blo(r1.z), w, a12); a13 = fmaf(bhi(r1.z), w, a13);
    a14 = fmaf(blo(r1.w), w, a14); a15 = fmaf(bhi(r1.w), w, a15);
  }
  uint4 s0 = hb[(size_t)n * 2];
  uint4 s1 = hb[(size_t)n * 2 + 1];
  float di = dis[n];
  a0  = (a0  + blo(s0.x)) * di;  a1  = (a1  + bhi(s0.x)) * di;
  a2  = (a2  + blo(s0.y)) * di;  a3  = (a3  + bhi(s0.y)) * di;
  a4  = (a4  + blo(s0.z)) * di;  a5  = (a5  + bhi(s0.z)) * di;
  a6  = (a6  + blo(s0.w)) * di;  a7  = (a7  + bhi(s0.w)) * di;
  a8  = (a8  + blo(s1.x)) * di;  a9  = (a9  + bhi(s1.x)) * di;
  a10 = (a10 + blo(s1.y)) * di;  a11 = (a11 + bhi(s1.y)) * di;
  a12 = (a12 + blo(s1.z)) * di;  a13 = (a13 + bhi(s1.z)) * di;
  a14 = (a14 + blo(s1.w)) * di;  a15 = (a15 + bhi(s1.w)) * di;
  if (LAYER == 1) {
    a0  = fmaxf(a0  + b1[0],  0.0f) * di;  a1  = fmaxf(a1  + b1[1],  0.0f) * di;
    a2  = fmaxf(a2  + b1[2],  0.0f) * di;  a3  = fmaxf(a3  + b1[3],  0.0f) * di;
    a4  = fmaxf(a4  + b1[4],  0.0f) * di;  a5  = fmaxf(a5  + b1[5],  0.0f) * di;
    a6  = fmaxf(a6  + b1[6],  0.0f) * di;  a7  = fmaxf(a7  + b1[7],  0.0f) * di;
    a8  = fmaxf(a8  + b1[8],  0.0f) * di;  a9  = fmaxf(a9  + b1[9],  0.0f) * di;
    a10 = fmaxf(a10 + b1[10], 0.0f) * di;  a11 = fmaxf(a11 + b1[11], 0.0f) * di;
    a12 = fmaxf(a12 + b1[12], 0.0f) * di;  a13 = fmaxf(a13 + b1[13], 0.0f) * di;
    a14 = fmaxf(a14 + b1[14], 0.0f) * di;  a15 = fmaxf(a15 + b1[15], 0.0f) * di;
    uint4 w0, w1;
    w0.x = pack2(a0,  a1);  w0.y = pack2(a2,  a3);
    w0.z = pack2(a4,  a5);  w0.w = pack2(a6,  a7);
    w1.x = pack2(a8,  a9);  w1.y = pack2(a10, a11);
    w1.z = pack2(a12, a13); w1.w = pack2(a14, a15);
    hb2[(size_t)n * 2]     = w0;
    hb2[(size_t)n * 2 + 1] = w1;
  } else {
    float4* gr = reinterpret_cast<float4*>(g + (size_t)n * HID);
    gr[0] = make_float4(a0,  a1,  a2,  a3);
    gr[1] = make_float4(a4,  a5,  a6,  a7);
    gr[2] = make_float4(a8,  a9,  a10, a11);
    gr[3] = make_float4(a12, a13, a14, a15);
  }
}

// ---- out = log_softmax(g @ W2 + b2), thread-per-node ----
__global__ void k_out(const float* __restrict__ g, const float* __restrict__ W2,
                      const float* __restrict__ b2, float* __restrict__ out, int N) {
  int n = blockIdx.x * blockDim.x + threadIdx.x;
  if (n >= N) return;
  float gv[HID];
#pragma unroll
  for (int j = 0; j < HID; ++j) gv[j] = g[(size_t)n * HID + j];
  float o[NCLS];
#pragma unroll
  for (int c = 0; c < NCLS; ++c) o[c] = b2[c];
#pragma unroll
  for (int j = 0; j < HID; ++j) {
    float gj = gv[j];
    const float* wr = W2 + (size_t)j * NCLS;
#pragma unroll
    for (int c = 0; c < NCLS; ++c) o[c] = fmaf(gj, wr[c], o[c]);
  }
  float m = o[0];
#pragma unroll
  for (int c = 1; c < NCLS; ++c) m = fmaxf(m, o[c]);
  float ss = 0.0f;
#pragma unroll
  for (int c = 0; c < NCLS; ++c) ss += expf(o[c] - m);
  float lse = m + logf(ss);
  float* orow = out + (size_t)n * NCLS;
#pragma unroll
  for (int c = 0; c < NCLS; ++c) orow[c] = o[c] - lse;
}

extern "C" void kernel_launch(void* const* d_in, const int* in_sizes, int n_in,
                              void* d_out, int out_size, void* d_ws, size_t ws_size,
                              hipStream_t stream) {
  const float* x  = (const float*)d_in[0];
  const int*   ei = (const int*)d_in[1];
  const float* ew = (const float*)d_in[2];
  const float* W1 = (const float*)d_in[3];
  const float* b1 = (const float*)d_in[4];
  const float* W2 = (const float*)d_in[5];
  const float* b2 = (const float*)d_in[6];
  float* out = (float*)d_out;

  const int N = in_sizes[0] / F_IN;   // 100000
  const int E = in_sizes[2];          // 3200000
  const int* src = ei;
  const int* dst = ei + E;

  const int NB    = (N + 127) >> 7;            // 782 buckets (<= BMAX)
  const int NBLK  = (E + CHUNK - 1) / CHUNK;   // 782 chunks
  const int NBLKp = (NBLK + 31) & ~31;         // 800
  const long long SCT = (long long)NB * NBLKp + 1;
  const int Npad  = (int)((SCT + 1023) & ~1023LL);
  const int nbScan = Npad / 1024;
  const int Nr    = (NB * 128 + 256 + 255) & ~255;  // rs/dis region (covers NB*128+1)

  // ws layout (4B words):
  // counts[Npad] | bsum[1024] | dis[Nr] | rs[Nr] | hb1[N*8] | hb2[N*8] | g[N*16] | payload[2E]
  int* counts = (int*)d_ws;
  int* bsum   = counts + Npad;
  float* dis  = (float*)(bsum + 1024);
  int* rs     = (int*)(dis + Nr);
  uint4* hb1  = (uint4*)(rs + Nr);
  uint4* hb2  = hb1 + (size_t)N * 2;
  float* g    = (float*)(hb2 + (size_t)N * 2);
  uint2* payload = (uint2*)(g + (size_t)N * HID);

  hipMemsetAsync(counts, 0, (size_t)Npad * sizeof(int), stream);
  k_count<<<NBLK, 256, 0, stream>>>(dst, counts, E, NB, NBLKp);
  k_scanA<<<nbScan, 256, 0, stream>>>(counts, bsum);
  k_scanB<<<1, 1024, 0, stream>>>(bsum, nbScan);
  k_scanC<<<nbScan, 256, 0, stream>>>(counts, bsum);
  k_scatter<<<NBLK, 256, 0, stream>>>(src, dst, ew, counts, payload, E, NB, NBLKp);
  k_sortb<<<NB, 256, 0, stream>>>(payload, counts, rs, dis, N, NBLKp);
  k_gemm1<<<(N + GR - 1) / GR, 256, 0, stream>>>(x, W1, dis, hb1, N);
  k_aggn<1><<<(N + 255) / 256, 256, 0, stream>>>(payload, rs, hb1, dis, b1, hb2, nullptr, N);
  k_aggn<2><<<(N + 255) / 256, 256, 0, stream>>>(payload, rs, hb2, dis, nullptr, nullptr, g, N);
  k_out<<<(N + 255) / 256, 256, 0, stream>>>(g, W2, b2, out, N);
}

// Round 8
// 393.167 us; speedup vs baseline: 1.0727x; 1.0727x over previous
//
#include <hip/hip_runtime.h>
#include <hip/hip_bf16.h>

constexpr int F_IN  = 512;
constexpr int HID   = 16;
constexpr int NCLS  = 40;
constexpr int CHUNK = 4096;   // edges per count/scatter block
constexpr int BMAX  = 800;    // max buckets (N=100000 -> NB=782)
constexpr int SMAX  = 6144;   // max edges per bucket (mean 4096, sd 64 -> 32 sigma)
constexpr int GR    = 64;     // fallback gemm rows per block
constexpr int NP    = 100096; // N padded to multiple of 128 (transpose tiles)

// ---- Pass A: per-chunk histogram of dst buckets (LDS atomics only) ----
__global__ void k_count(const int* __restrict__ dst, int* __restrict__ counts,
                        int E, int NB, int NBLKp) {
  __shared__ int hist[BMAX];
  int t = threadIdx.x;
  for (int b = t; b < BMAX; b += 256) hist[b] = 0;
  __syncthreads();
  int base = blockIdx.x * CHUNK;
  for (int i = 0; i < CHUNK; i += 256) {
    int e = base + i + t;
    if (e < E) atomicAdd(&hist[dst[e] >> 7], 1);
  }
  __syncthreads();
  for (int b = t; b < NB; b += 256) counts[b * NBLKp + blockIdx.x] = hist[b];
}

// ---- scan over counts (bucket-major), 3 stages, in-place ----
__global__ void k_scanA(const int* __restrict__ a, int* __restrict__ bsum) {
  __shared__ int sd[256];
  int t = threadIdx.x;
  int4 v = reinterpret_cast<const int4*>(a)[blockIdx.x * 256 + t];
  sd[t] = v.x + v.y + v.z + v.w;
  __syncthreads();
  for (int off = 128; off > 0; off >>= 1) {
    if (t < off) sd[t] += sd[t + off];
    __syncthreads();
  }
  if (!t) bsum[blockIdx.x] = sd[0];
}

__global__ void k_scanB(int* __restrict__ bsum, int nb) {
  __shared__ int sd[1024];
  int t = threadIdx.x;
  int v = (t < nb) ? bsum[t] : 0;
  sd[t] = v;
  __syncthreads();
  for (int off = 1; off < 1024; off <<= 1) {
    int add = (t >= off) ? sd[t - off] : 0;
    __syncthreads();
    sd[t] += add;
    __syncthreads();
  }
  if (t < nb) bsum[t] = sd[t] - v;  // exclusive
}

__global__ void k_scanC(int* __restrict__ a, const int* __restrict__ bsum) {
  __shared__ int sd[256];
  int t = threadIdx.x;
  int4 v = reinterpret_cast<int4*>(a)[blockIdx.x * 256 + t];
  int ts = v.x + v.y + v.z + v.w;
  sd[t] = ts;
  __syncthreads();
  for (int off = 1; off < 256; off <<= 1) {
    int add = (t >= off) ? sd[t - off] : 0;
    __syncthreads();
    sd[t] += add;
    __syncthreads();
  }
  int pre = bsum[blockIdx.x] + sd[t] - ts;
  int4 w;
  w.x = pre; w.y = pre + v.x; w.z = w.y + v.y; w.w = w.z + v.z;
  reinterpret_cast<int4*>(a)[blockIdx.x * 256 + t] = w;
}

// ---- Pass B: scatter edges into bucket-sorted payload (LDS cursors only) ----
__global__ void k_scatter(const int* __restrict__ src, const int* __restrict__ dst,
                          const float* __restrict__ ew, const int* __restrict__ counts,
                          uint2* __restrict__ payload, int E, int NB, int NBLKp) {
  __shared__ int cur[BMAX];
  int t = threadIdx.x;
  for (int b = t; b < NB; b += 256) cur[b] = counts[b * NBLKp + blockIdx.x];
  __syncthreads();
  int base = blockIdx.x * CHUNK;
  for (int i = 0; i < CHUNK; i += 256) {
    int e = base + i + t;
    if (e < E) {
      int s = src[e], d = dst[e];
      float w = ew[e];
      int pos = atomicAdd(&cur[d >> 7], 1);
      payload[pos] = make_uint2(((unsigned)s << 7) | (unsigned)(d & 127),
                                __float_as_uint(w));
    }
  }
}

// ---- Pass C: per-bucket in-place counting sort by dst-low-7 -> per-node CSR.
//      Also computes deg/dis (folds old k_degb). LDS only; no global atomics. ----
__global__ void __launch_bounds__(256)
k_sortb(uint2* __restrict__ payload, const int* __restrict__ counts,
        int* __restrict__ rs, float* __restrict__ dis, int N, int NBLKp) {
  __shared__ uint2 ebuf[SMAX];
  __shared__ int hcnt[128];
  __shared__ int sc[128];
  __shared__ float dgs[128];
  int t = threadIdx.x;
  if (t < 128) { hcnt[t] = 0; dgs[t] = 1.0f; }
  __syncthreads();
  int beg = counts[blockIdx.x * NBLKp];
  int end = counts[(blockIdx.x + 1) * NBLKp];
  int sz = end - beg;
  for (int i = t; i < sz; i += 256) {
    uint2 p = payload[beg + i];
    ebuf[i] = p;
    atomicAdd(&hcnt[p.x & 127], 1);
    atomicAdd(&dgs[p.x & 127], __uint_as_float(p.y));
  }
  __syncthreads();
  int v = (t < 128) ? hcnt[t] : 0;
  if (t < 128) sc[t] = v;
  __syncthreads();
  for (int off = 1; off < 128; off <<= 1) {
    int add = (t < 128 && t >= off) ? sc[t - off] : 0;
    __syncthreads();
    if (t < 128) sc[t] += add;
    __syncthreads();
  }
  int base = blockIdx.x * 128;
  if (t < 128) {
    int st = sc[t] - v;        // exclusive prefix within bucket
    hcnt[t] = st;              // reuse as relative cursor
    rs[base + t] = beg + st;
    int n = base + t;
    if (n < N) dis[n] = rsqrtf(dgs[t]);
  }
  if (t == 0) rs[base + 128] = end;
  __syncthreads();
  for (int i = t; i < sz; i += 256) {
    uint2 p = ebuf[i];
    int pos = beg + atomicAdd(&hcnt[p.x & 127], 1);
    payload[pos] = make_uint2(p.x >> 7, p.y);   // store plain src index + weight
  }
}

__device__ __forceinline__ float blo(unsigned u) { return __uint_as_float(u << 16); }
__device__ __forceinline__ float bhi(unsigned u) { return __uint_as_float(u & 0xffff0000u); }
__device__ __forceinline__ unsigned pack2(float lo, float hi) {
  __hip_bfloat16 l = __float2bfloat16(lo), h = __float2bfloat16(hi);
  unsigned short ul = *reinterpret_cast<unsigned short*>(&l);
  unsigned short uh = *reinterpret_cast<unsigned short*>(&h);
  return (unsigned)ul | ((unsigned)uh << 16);
}

// ---- transpose x[N][512] f32 -> xT[512][NP] bf16, tiles 128n x 64k ----
__global__ void __launch_bounds__(256)
k_xpose(const float* __restrict__ x, unsigned* __restrict__ xtb32, int N) {
  __shared__ float tile[128 * 65];
  int t = threadIdx.x;
  int nb = (blockIdx.x >> 3) * 128;        // node base
  int k0 = (blockIdx.x & 7) * 64;          // k base
  // stage: coalesced row reads (16 float4 per row)
#pragma unroll
  for (int i = 0; i < 8; ++i) {
    int f = t + 256 * i;                    // 0..2047 float4 slots
    int rr = f >> 4;                        // row 0..127
    int off = f & 15;                       // float4 within 64-k chunk
    int n = nb + rr;
    float4 v = make_float4(0.f, 0.f, 0.f, 0.f);
    if (n < N) v = *reinterpret_cast<const float4*>(x + (size_t)n * F_IN + k0 + off * 4);
    int c = off * 4;
    tile[rr * 65 + c + 0] = v.x;
    tile[rr * 65 + c + 1] = v.y;
    tile[rr * 65 + c + 2] = v.z;
    tile[rr * 65 + c + 3] = v.w;
  }
  __syncthreads();
  // write: lane l handles node pair (2l, 2l+1); wave w + pass p -> k index
  int l = t & 63, wv = t >> 6;
#pragma unroll
  for (int p = 0; p < 16; ++p) {
    int kk = wv * 16 + p;
    unsigned u = pack2(tile[(2 * l) * 65 + kk], tile[(2 * l + 1) * 65 + kk]);
    xtb32[(size_t)(k0 + kk) * (NP / 2) + (nb >> 1) + l] = u;
  }
}

// ---- h1' = (x @ W1) * dis, from xT(bf16): fully coalesced.
//      Block: 128 nodes; 4 waves = 4 k-slices of 128; lane = node pair. ----
__global__ void __launch_bounds__(256)
k_gemm1b(const unsigned* __restrict__ xtb32, const float* __restrict__ W1,
         const float* __restrict__ dis, uint4* __restrict__ hb1, int N) {
  __shared__ float ps[4 * 128 * 17];
  int t = threadIdx.x;
  int l = t & 63, s = t >> 6;
  int nb = blockIdx.x * 128;
  const unsigned* xp = xtb32 + (size_t)(s * 128) * (NP / 2) + (nb >> 1) + l;
  const float* wp = W1 + s * 128 * HID;
  float a0[HID], a1[HID];
#pragma unroll
  for (int j = 0; j < HID; ++j) { a0[j] = 0.0f; a1[j] = 0.0f; }
#pragma unroll 4
  for (int kk = 0; kk < 128; ++kk) {
    unsigned u = xp[(size_t)kk * (NP / 2)];
    float x0 = blo(u), x1 = bhi(u);
    const float* wr = wp + kk * HID;
#pragma unroll
    for (int j = 0; j < HID; ++j) {
      float w = wr[j];
      a0[j] = fmaf(x0, w, a0[j]);
      a1[j] = fmaf(x1, w, a1[j]);
    }
  }
#pragma unroll
  for (int j = 0; j < HID; ++j) {
    ps[(s * 128 + 2 * l) * 17 + j]     = a0[j];
    ps[(s * 128 + 2 * l + 1) * 17 + j] = a1[j];
  }
  __syncthreads();
  if (t < 128) {
    int n = nb + t;
    if (n < N) {
      float di = dis[n];
      float o[HID];
#pragma unroll
      for (int j = 0; j < HID; ++j)
        o[j] = (ps[t * 17 + j] + ps[(128 + t) * 17 + j] +
                ps[(256 + t) * 17 + j] + ps[(384 + t) * 17 + j]) * di;
      uint4 w0, w1;
      w0.x = pack2(o[0],  o[1]);  w0.y = pack2(o[2],  o[3]);
      w0.z = pack2(o[4],  o[5]);  w0.w = pack2(o[6],  o[7]);
      w1.x = pack2(o[8],  o[9]);  w1.y = pack2(o[10], o[11]);
      w1.z = pack2(o[12], o[13]); w1.w = pack2(o[14], o[15]);
      hb1[(size_t)n * 2]     = w0;
      hb1[(size_t)n * 2 + 1] = w1;
    }
  }
}

// ---- fallback gemm (r6 version): thread-per-row, used if ws too small ----
__global__ void k_gemm1(const float* __restrict__ x, const float* __restrict__ W1,
                        const float* __restrict__ dis, uint4* __restrict__ hb1, int N) {
  int n = blockIdx.x * blockDim.x + threadIdx.x;
  if (n >= N) return;
  const float* xr = x + (size_t)n * F_IN;
  float acc[HID];
#pragma unroll
  for (int j = 0; j < HID; ++j) acc[j] = 0.0f;
  for (int k = 0; k < F_IN; k += 16) {
    float4 q0 = *reinterpret_cast<const float4*>(xr + k);
    float4 q1 = *reinterpret_cast<const float4*>(xr + k + 4);
    float4 q2 = *reinterpret_cast<const float4*>(xr + k + 8);
    float4 q3 = *reinterpret_cast<const float4*>(xr + k + 12);
    float xv[16] = {q0.x, q0.y, q0.z, q0.w, q1.x, q1.y, q1.z, q1.w,
                    q2.x, q2.y, q2.z, q2.w, q3.x, q3.y, q3.z, q3.w};
#pragma unroll
    for (int kk = 0; kk < 16; ++kk) {
      float xx = xv[kk];
      const float* wr = W1 + (size_t)(k + kk) * HID;
#pragma unroll
      for (int j = 0; j < HID; ++j) acc[j] = fmaf(xx, wr[j], acc[j]);
    }
  }
  float di = dis[n];
  uint4 w0, w1;
  w0.x = pack2(acc[0] * di,  acc[1] * di);  w0.y = pack2(acc[2] * di,  acc[3] * di);
  w0.z = pack2(acc[4] * di,  acc[5] * di);  w0.w = pack2(acc[6] * di,  acc[7] * di);
  w1.x = pack2(acc[8] * di,  acc[9] * di);  w1.y = pack2(acc[10] * di, acc[11] * di);
  w1.z = pack2(acc[12] * di, acc[13] * di); w1.w = pack2(acc[14] * di, acc[15] * di);
  hb1[(size_t)n * 2]     = w0;
  hb1[(size_t)n * 2 + 1] = w1;
}

// ---- aggregation: ONE NODE PER LANE, 16 f32 register accumulators, zero LDS. ----
template <int LAYER>
__global__ void __launch_bounds__(256)
k_aggn(const uint2* __restrict__ payload, const int* __restrict__ rs,
       const uint4* __restrict__ hb, const float* __restrict__ dis,
       const float* __restrict__ b1, uint4* __restrict__ hb2,
       float* __restrict__ g, int N) {
  int n = blockIdx.x * 256 + threadIdx.x;
  if (n >= N) return;
  int e0 = rs[n], e1 = rs[n + 1];
  float a0 = 0, a1 = 0, a2 = 0, a3 = 0, a4 = 0, a5 = 0, a6 = 0, a7 = 0;
  float a8 = 0, a9 = 0, a10 = 0, a11 = 0, a12 = 0, a13 = 0, a14 = 0, a15 = 0;
#pragma unroll 2
  for (int e = e0; e < e1; ++e) {
    uint2 p = payload[e];
    const uint4* row = hb + ((size_t)p.x * 2);
    uint4 r0 = row[0];
    uint4 r1 = row[1];
    float w = __uint_as_float(p.y);
    a0  = fmaf(blo(r0.x), w, a0);  a1  = fmaf(bhi(r0.x), w, a1);
    a2  = fmaf(blo(r0.y), w, a2);  a3  = fmaf(bhi(r0.y), w, a3);
    a4  = fmaf(blo(r0.z), w, a4);  a5  = fmaf(bhi(r0.z), w, a5);
    a6  = fmaf(blo(r0.w), w, a6);  a7  = fmaf(bhi(r0.w), w, a7);
    a8  = fmaf(blo(r1.x), w, a8);  a9  = fmaf(bhi(r1.x), w, a9);
    a10 = fmaf(blo(r1.y), w, a10); a11 = fmaf(bhi(r1.y), w, a11);
    a12 = fmaf(blo(r1.z), w, a12); a13 = fmaf(bhi(r1.z), w, a13);
    a14 = fmaf(blo(r1.w), w, a14); a15 = fmaf(bhi(r1.w), w, a15);
  }
  uint4 s0 = hb[(size_t)n * 2];
  uint4 s1 = hb[(size_t)n * 2 + 1];
  float di = dis[n];
  a0  = (a0  + blo(s0.x)) * di;  a1  = (a1  + bhi(s0.x)) * di;
  a2  = (a2  + blo(s0.y)) * di;  a3  = (a3  + bhi(s0.y)) * di;
  a4  = (a4  + blo(s0.z)) * di;  a5  = (a5  + bhi(s0.z)) * di;
  a6  = (a6  + blo(s0.w)) * di;  a7  = (a7  + bhi(s0.w)) * di;
  a8  = (a8  + blo(s1.x)) * di;  a9  = (a9  + bhi(s1.x)) * di;
  a10 = (a10 + blo(s1.y)) * di;  a11 = (a11 + bhi(s1.y)) * di;
  a12 = (a12 + blo(s1.z)) * di;  a13 = (a13 + bhi(s1.z)) * di;
  a14 = (a14 + blo(s1.w)) * di;  a15 = (a15 + bhi(s1.w)) * di;
  if (LAYER == 1) {
    a0  = fmaxf(a0  + b1[0],  0.0f) * di;  a1  = fmaxf(a1  + b1[1],  0.0f) * di;
    a2  = fmaxf(a2  + b1[2],  0.0f) * di;  a3  = fmaxf(a3  + b1[3],  0.0f) * di;
    a4  = fmaxf(a4  + b1[4],  0.0f) * di;  a5  = fmaxf(a5  + b1[5],  0.0f) * di;
    a6  = fmaxf(a6  + b1[6],  0.0f) * di;  a7  = fmaxf(a7  + b1[7],  0.0f) * di;
    a8  = fmaxf(a8  + b1[8],  0.0f) * di;  a9  = fmaxf(a9  + b1[9],  0.0f) * di;
    a10 = fmaxf(a10 + b1[10], 0.0f) * di;  a11 = fmaxf(a11 + b1[11], 0.0f) * di;
    a12 = fmaxf(a12 + b1[12], 0.0f) * di;  a13 = fmaxf(a13 + b1[13], 0.0f) * di;
    a14 = fmaxf(a14 + b1[14], 0.0f) * di;  a15 = fmaxf(a15 + b1[15], 0.0f) * di;
    uint4 w0, w1;
    w0.x = pack2(a0,  a1);  w0.y = pack2(a2,  a3);
    w0.z = pack2(a4,  a5);  w0.w = pack2(a6,  a7);
    w1.x = pack2(a8,  a9);  w1.y = pack2(a10, a11);
    w1.z = pack2(a12, a13); w1.w = pack2(a14, a15);
    hb2[(size_t)n * 2]     = w0;
    hb2[(size_t)n * 2 + 1] = w1;
  } else {
    float4* gr = reinterpret_cast<float4*>(g + (size_t)n * HID);
    gr[0] = make_float4(a0,  a1,  a2,  a3);
    gr[1] = make_float4(a4,  a5,  a6,  a7);
    gr[2] = make_float4(a8,  a9,  a10, a11);
    gr[3] = make_float4(a12, a13, a14, a15);
  }
}

// ---- out = log_softmax(g @ W2 + b2), thread-per-node ----
__global__ void k_out(const float* __restrict__ g, const float* __restrict__ W2,
                      const float* __restrict__ b2, float* __restrict__ out, int N) {
  int n = blockIdx.x * blockDim.x + threadIdx.x;
  if (n >= N) return;
  float gv[HID];
#pragma unroll
  for (int j = 0; j < HID; ++j) gv[j] = g[(size_t)n * HID + j];
  float o[NCLS];
#pragma unroll
  for (int c = 0; c < NCLS; ++c) o[c] = b2[c];
#pragma unroll
  for (int j = 0; j < HID; ++j) {
    float gj = gv[j];
    const float* wr = W2 + (size_t)j * NCLS;
#pragma unroll
    for (int c = 0; c < NCLS; ++c) o[c] = fmaf(gj, wr[c], o[c]);
  }
  float m = o[0];
#pragma unroll
  for (int c = 1; c < NCLS; ++c) m = fmaxf(m, o[c]);
  float ss = 0.0f;
#pragma unroll
  for (int c = 0; c < NCLS; ++c) ss += expf(o[c] - m);
  float lse = m + logf(ss);
  float* orow = out + (size_t)n * NCLS;
#pragma unroll
  for (int c = 0; c < NCLS; ++c) orow[c] = o[c] - lse;
}

extern "C" void kernel_launch(void* const* d_in, const int* in_sizes, int n_in,
                              void* d_out, int out_size, void* d_ws, size_t ws_size,
                              hipStream_t stream) {
  const float* x  = (const float*)d_in[0];
  const int*   ei = (const int*)d_in[1];
  const float* ew = (const float*)d_in[2];
  const float* W1 = (const float*)d_in[3];
  const float* b1 = (const float*)d_in[4];
  const float* W2 = (const float*)d_in[5];
  const float* b2 = (const float*)d_in[6];
  float* out = (float*)d_out;

  const int N = in_sizes[0] / F_IN;   // 100000
  const int E = in_sizes[2];          // 3200000
  const int* src = ei;
  const int* dst = ei + E;

  const int NB    = (N + 127) >> 7;            // 782 buckets (<= BMAX)
  const int NBLK  = (E + CHUNK - 1) / CHUNK;   // 782 chunks
  const int NBLKp = (NBLK + 31) & ~31;         // 800
  const long long SCT = (long long)NB * NBLKp + 1;
  const int Npad  = (int)((SCT + 1023) & ~1023LL);
  const int nbScan = Npad / 1024;
  const int Nr    = (NB * 128 + 256 + 255) & ~255;

  // ws layout (4B words):
  // counts[Npad] | bsum[1024] | dis[Nr] | rs[Nr] | hb1[N*8] | hb2[N*8] | g[N*16] | payload[2E] | xtb[NP*512/2]
  int* counts = (int*)d_ws;
  int* bsum   = counts + Npad;
  float* dis  = (float*)(bsum + 1024);
  int* rs     = (int*)(dis + Nr);
  uint4* hb1  = (uint4*)(rs + Nr);
  uint4* hb2  = hb1 + (size_t)N * 2;
  float* g    = (float*)(hb2 + (size_t)N * 2);
  uint2* payload = (uint2*)(g + (size_t)N * HID);
  unsigned* xtb32 = (unsigned*)(payload + (size_t)E);
  size_t need = ((char*)(xtb32 + (size_t)NP * F_IN / 2)) - (char*)d_ws;
  bool fast = (ws_size >= need);

  hipMemsetAsync(counts, 0, (size_t)Npad * sizeof(int), stream);
  k_count<<<NBLK, 256, 0, stream>>>(dst, counts, E, NB, NBLKp);
  k_scanA<<<nbScan, 256, 0, stream>>>(counts, bsum);
  k_scanB<<<1, 1024, 0, stream>>>(bsum, nbScan);
  k_scanC<<<nbScan, 256, 0, stream>>>(counts, bsum);
  k_scatter<<<NBLK, 256, 0, stream>>>(src, dst, ew, counts, payload, E, NB, NBLKp);
  k_sortb<<<NB, 256, 0, stream>>>(payload, counts, rs, dis, N, NBLKp);
  if (fast) {
    k_xpose<<<(NP / 128) * 8, 256, 0, stream>>>(x, xtb32, N);
    k_gemm1b<<<NP / 128, 256, 0, stream>>>(xtb32, W1, dis, hb1, N);
  } else {
    k_gemm1<<<(N + 255) / 256, 256, 0, stream>>>(x, W1, dis, hb1, N);
  }
  k_aggn<1><<<(N + 255) / 256, 256, 0, stream>>>(payload, rs, hb1, dis, b1, hb2, nullptr, N);
  k_aggn<2><<<(N + 255) / 256, 256, 0, stream>>>(payload, rs, hb2, dis, nullptr, nullptr, g, N);
  k_out<<<(N + 255) / 256, 256, 0, stream>>>(g, W2, b2, out, N);
}

// Round 9
// 341.277 us; speedup vs baseline: 1.2358x; 1.1520x over previous
//
#include <hip/hip_runtime.h>
#include <hip/hip_bf16.h>

constexpr int F_IN  = 512;
constexpr int HID   = 16;
constexpr int NCLS  = 40;
constexpr int CHUNK = 4096;   // edges per chunk
constexpr int BMAX  = 800;    // max buckets (N=100000 -> NB=782)
constexpr int SMAX  = 6144;   // max edges per bucket
constexpr int NP    = 100096; // N padded to multiple of 128 (transpose tiles)

// ---- zero the scan pad [lo,hi) of counts ----
__global__ void k_zpad(int* __restrict__ counts, int lo, int hi) {
  int i = lo + blockIdx.x * 256 + threadIdx.x;
  if (i < hi) counts[i] = 0;
}

// ---- Pass A: per-chunk histogram of dst buckets (LDS atomics only) ----
__global__ void k_count(const int* __restrict__ dst, int* __restrict__ counts,
                        int E, int NB, int NBLK) {
  __shared__ int hist[BMAX];
  int t = threadIdx.x;
  for (int b = t; b < BMAX; b += 256) hist[b] = 0;
  __syncthreads();
  int base = blockIdx.x * CHUNK;
  for (int i = 0; i < CHUNK; i += 256) {
    int e = base + i + t;
    if (e < E) atomicAdd(&hist[dst[e] >> 7], 1);
  }
  __syncthreads();
  for (int b = t; b < NB; b += 256) counts[b * NBLK + blockIdx.x] = hist[b];
}

// ---- scan over counts (bucket-major), 3 stages, in-place ----
__global__ void k_scanA(const int* __restrict__ a, int* __restrict__ bsum) {
  __shared__ int sd[256];
  int t = threadIdx.x;
  int4 v = reinterpret_cast<const int4*>(a)[blockIdx.x * 256 + t];
  sd[t] = v.x + v.y + v.z + v.w;
  __syncthreads();
  for (int off = 128; off > 0; off >>= 1) {
    if (t < off) sd[t] += sd[t + off];
    __syncthreads();
  }
  if (!t) bsum[blockIdx.x] = sd[0];
}

__global__ void k_scanB(int* __restrict__ bsum, int nb) {
  __shared__ int sd[1024];
  int t = threadIdx.x;
  int v = (t < nb) ? bsum[t] : 0;
  sd[t] = v;
  __syncthreads();
  for (int off = 1; off < 1024; off <<= 1) {
    int add = (t >= off) ? sd[t - off] : 0;
    __syncthreads();
    sd[t] += add;
    __syncthreads();
  }
  if (t < nb) bsum[t] = sd[t] - v;  // exclusive
}

__global__ void k_scanC(int* __restrict__ a, const int* __restrict__ bsum) {
  __shared__ int sd[256];
  int t = threadIdx.x;
  int4 v = reinterpret_cast<int4*>(a)[blockIdx.x * 256 + t];
  int ts = v.x + v.y + v.z + v.w;
  sd[t] = ts;
  __syncthreads();
  for (int off = 1; off < 256; off <<= 1) {
    int add = (t >= off) ? sd[t - off] : 0;
    __syncthreads();
    sd[t] += add;
    __syncthreads();
  }
  int pre = bsum[blockIdx.x] + sd[t] - ts;
  int4 w;
  w.x = pre; w.y = pre + v.x; w.z = w.y + v.y; w.w = w.z + v.z;
  reinterpret_cast<int4*>(a)[blockIdx.x * 256 + t] = w;
}

// ---- Pass B: chunk-local LDS counting sort by bucket; STREAMING writes.
//      payloadA[c*CHUNK + i] grouped by bucket within chunk; segs[c][b] = local offsets ----
__global__ void __launch_bounds__(256)
k_scat2(const int* __restrict__ src, const int* __restrict__ dst,
        const float* __restrict__ ew, uint2* __restrict__ payloadA,
        int* __restrict__ segs, int E, int NB) {
  __shared__ uint2 ebuf[CHUNK];
  __shared__ int hist[1024];
  __shared__ int sc[256];
  int t = threadIdx.x;
  int c = blockIdx.x;
  int cbase = c * CHUNK;
  int sz = min(CHUNK, E - cbase);
#pragma unroll
  for (int i = 0; i < 4; ++i) hist[t + 256 * i] = 0;
  __syncthreads();
  uint2 pk[16];
  int key[16];
#pragma unroll
  for (int r = 0; r < 16; ++r) {
    int i = r * 256 + t;
    int e = cbase + i;
    if (i < sz) {
      int s = src[e], d = dst[e];
      pk[r] = make_uint2(((unsigned)s << 7) | (unsigned)(d & 127),
                         __float_as_uint(ew[e]));
      key[r] = d >> 7;
      atomicAdd(&hist[key[r]], 1);
    } else {
      key[r] = -1;
    }
  }
  __syncthreads();
  // exclusive scan of hist[1024]: 4 entries per thread
  int h0 = hist[4 * t], h1 = hist[4 * t + 1], h2 = hist[4 * t + 2], h3 = hist[4 * t + 3];
  int tsum = h0 + h1 + h2 + h3;
  sc[t] = tsum;
  __syncthreads();
  for (int off = 1; off < 256; off <<= 1) {
    int add = (t >= off) ? sc[t - off] : 0;
    __syncthreads();
    sc[t] += add;
    __syncthreads();
  }
  int pre = sc[t] - tsum;
  __syncthreads();
  hist[4 * t]     = pre;
  hist[4 * t + 1] = pre + h0;
  hist[4 * t + 2] = pre + h0 + h1;
  hist[4 * t + 3] = pre + h0 + h1 + h2;
  __syncthreads();
  // write segs (prefix) BEFORE pass2 mutates hist
  size_t sb = (size_t)c * (NB + 1);
  for (int b = t; b < NB; b += 256) segs[sb + b] = hist[b];
  if (t == 0) segs[sb + NB] = sz;
  __syncthreads();
#pragma unroll
  for (int r = 0; r < 16; ++r) {
    if (key[r] >= 0) {
      int pos = atomicAdd(&hist[key[r]], 1);
      ebuf[pos] = pk[r];
    }
  }
  __syncthreads();
  for (int i = t; i < sz; i += 256) payloadA[cbase + i] = ebuf[i];
}

// ---- Pass C: per-bucket assembly (gather chunk segments) + node counting sort.
//      Streaming write of bucket-major payloadB + rs + dis. ----
__global__ void __launch_bounds__(256)
k_sortb2(const uint2* __restrict__ payloadA, const int* __restrict__ segs,
         const int* __restrict__ cnts, uint2* __restrict__ payloadB,
         int* __restrict__ rs, float* __restrict__ dis,
         int N, int NB, int NBLK) {
  __shared__ uint2 ebuf[SMAX];
  __shared__ int hcnt[128];
  __shared__ int scn[128];
  __shared__ float dgs[128];
  int t = threadIdx.x;
  int b = blockIdx.x;
  if (t < 128) { hcnt[t] = 0; dgs[t] = 1.0f; }
  __syncthreads();
  int beg = cnts[b * NBLK];
  int end = cnts[b * NBLK + NBLK];   // == start of bucket b+1 (pad -> E for last)
  // gather this bucket's segment from every chunk
  for (int c = t; c < NBLK; c += 256) {
    int rel = cnts[b * NBLK + c] - beg;
    size_t sb = (size_t)c * (NB + 1) + b;
    int s0 = segs[sb], s1 = segs[sb + 1];
    int gsrc = c * CHUNK + s0;
    for (int k = 0; k < s1 - s0; ++k) {
      uint2 p = payloadA[gsrc + k];
      ebuf[rel + k] = p;
      atomicAdd(&hcnt[p.x & 127], 1);
      atomicAdd(&dgs[p.x & 127], __uint_as_float(p.y));
    }
  }
  __syncthreads();
  int v = (t < 128) ? hcnt[t] : 0;
  if (t < 128) scn[t] = v;
  __syncthreads();
  for (int off = 1; off < 128; off <<= 1) {
    int add = (t < 128 && t >= off) ? scn[t - off] : 0;
    __syncthreads();
    if (t < 128) scn[t] += add;
    __syncthreads();
  }
  int base = b * 128;
  if (t < 128) {
    int st = scn[t] - v;
    hcnt[t] = st;
    rs[base + t] = beg + st;
    int n = base + t;
    if (n < N) dis[n] = rsqrtf(dgs[t]);
  }
  if (t == 0) rs[base + 128] = end;
  __syncthreads();
  int sz = end - beg;
  for (int i = t; i < sz; i += 256) {
    uint2 p = ebuf[i];
    int pos = beg + atomicAdd(&hcnt[p.x & 127], 1);
    payloadB[pos] = make_uint2(p.x >> 7, p.y);
  }
}

__device__ __forceinline__ float blo(unsigned u) { return __uint_as_float(u << 16); }
__device__ __forceinline__ float bhi(unsigned u) { return __uint_as_float(u & 0xffff0000u); }
__device__ __forceinline__ unsigned pack2(float lo, float hi) {
  __hip_bfloat16 l = __float2bfloat16(lo), h = __float2bfloat16(hi);
  unsigned short ul = *reinterpret_cast<unsigned short*>(&l);
  unsigned short uh = *reinterpret_cast<unsigned short*>(&h);
  return (unsigned)ul | ((unsigned)uh << 16);
}

// ---- transpose x[N][512] f32 -> xT[512][NP] bf16, tiles 128n x 64k ----
__global__ void __launch_bounds__(256)
k_xpose(const float* __restrict__ x, unsigned* __restrict__ xtb32, int N) {
  __shared__ float tile[128 * 65];
  int t = threadIdx.x;
  int nb = (blockIdx.x >> 3) * 128;
  int k0 = (blockIdx.x & 7) * 64;
#pragma unroll
  for (int i = 0; i < 8; ++i) {
    int f = t + 256 * i;
    int rr = f >> 4;
    int off = f & 15;
    int n = nb + rr;
    float4 v = make_float4(0.f, 0.f, 0.f, 0.f);
    if (n < N) v = *reinterpret_cast<const float4*>(x + (size_t)n * F_IN + k0 + off * 4);
    int c = off * 4;
    tile[rr * 65 + c + 0] = v.x;
    tile[rr * 65 + c + 1] = v.y;
    tile[rr * 65 + c + 2] = v.z;
    tile[rr * 65 + c + 3] = v.w;
  }
  __syncthreads();
  int l = t & 63, wv = t >> 6;
#pragma unroll
  for (int p = 0; p < 16; ++p) {
    int kk = wv * 16 + p;
    unsigned u = pack2(tile[(2 * l) * 65 + kk], tile[(2 * l + 1) * 65 + kk]);
    xtb32[(size_t)(k0 + kk) * (NP / 2) + (nb >> 1) + l] = u;
  }
}

// ---- h1' = (x @ W1) * dis, from xT(bf16): fully coalesced ----
__global__ void __launch_bounds__(256)
k_gemm1b(const unsigned* __restrict__ xtb32, const float* __restrict__ W1,
         const float* __restrict__ dis, uint4* __restrict__ hb1, int N) {
  __shared__ float ps[4 * 128 * 17];
  int t = threadIdx.x;
  int l = t & 63, s = t >> 6;
  int nb = blockIdx.x * 128;
  const unsigned* xp = xtb32 + (size_t)(s * 128) * (NP / 2) + (nb >> 1) + l;
  const float* wp = W1 + s * 128 * HID;
  float a0[HID], a1[HID];
#pragma unroll
  for (int j = 0; j < HID; ++j) { a0[j] = 0.0f; a1[j] = 0.0f; }
#pragma unroll 4
  for (int kk = 0; kk < 128; ++kk) {
    unsigned u = xp[(size_t)kk * (NP / 2)];
    float x0 = blo(u), x1 = bhi(u);
    const float* wr = wp + kk * HID;
#pragma unroll
    for (int j = 0; j < HID; ++j) {
      float w = wr[j];
      a0[j] = fmaf(x0, w, a0[j]);
      a1[j] = fmaf(x1, w, a1[j]);
    }
  }
#pragma unroll
  for (int j = 0; j < HID; ++j) {
    ps[(s * 128 + 2 * l) * 17 + j]     = a0[j];
    ps[(s * 128 + 2 * l + 1) * 17 + j] = a1[j];
  }
  __syncthreads();
  if (t < 128) {
    int n = nb + t;
    if (n < N) {
      float di = dis[n];
      float o[HID];
#pragma unroll
      for (int j = 0; j < HID; ++j)
        o[j] = (ps[t * 17 + j] + ps[(128 + t) * 17 + j] +
                ps[(256 + t) * 17 + j] + ps[(384 + t) * 17 + j]) * di;
      uint4 w0, w1;
      w0.x = pack2(o[0],  o[1]);  w0.y = pack2(o[2],  o[3]);
      w0.z = pack2(o[4],  o[5]);  w0.w = pack2(o[6],  o[7]);
      w1.x = pack2(o[8],  o[9]);  w1.y = pack2(o[10], o[11]);
      w1.z = pack2(o[12], o[13]); w1.w = pack2(o[14], o[15]);
      hb1[(size_t)n * 2]     = w0;
      hb1[(size_t)n * 2 + 1] = w1;
    }
  }
}

// ---- fallback gemm: thread-per-row (used if ws too small) ----
__global__ void k_gemm1(const float* __restrict__ x, const float* __restrict__ W1,
                        const float* __restrict__ dis, uint4* __restrict__ hb1, int N) {
  int n = blockIdx.x * blockDim.x + threadIdx.x;
  if (n >= N) return;
  const float* xr = x + (size_t)n * F_IN;
  float acc[HID];
#pragma unroll
  for (int j = 0; j < HID; ++j) acc[j] = 0.0f;
  for (int k = 0; k < F_IN; k += 16) {
    float4 q0 = *reinterpret_cast<const float4*>(xr + k);
    float4 q1 = *reinterpret_cast<const float4*>(xr + k + 4);
    float4 q2 = *reinterpret_cast<const float4*>(xr + k + 8);
    float4 q3 = *reinterpret_cast<const float4*>(xr + k + 12);
    float xv[16] = {q0.x, q0.y, q0.z, q0.w, q1.x, q1.y, q1.z, q1.w,
                    q2.x, q2.y, q2.z, q2.w, q3.x, q3.y, q3.z, q3.w};
#pragma unroll
    for (int kk = 0; kk < 16; ++kk) {
      float xx = xv[kk];
      const float* wr = W1 + (size_t)(k + kk) * HID;
#pragma unroll
      for (int j = 0; j < HID; ++j) acc[j] = fmaf(xx, wr[j], acc[j]);
    }
  }
  float di = dis[n];
  uint4 w0, w1;
  w0.x = pack2(acc[0] * di,  acc[1] * di);  w0.y = pack2(acc[2] * di,  acc[3] * di);
  w0.z = pack2(acc[4] * di,  acc[5] * di);  w0.w = pack2(acc[6] * di,  acc[7] * di);
  w1.x = pack2(acc[8] * di,  acc[9] * di);  w1.y = pack2(acc[10] * di, acc[11] * di);
  w1.z = pack2(acc[12] * di, acc[13] * di); w1.w = pack2(acc[14] * di, acc[15] * di);
  hb1[(size_t)n * 2]     = w0;
  hb1[(size_t)n * 2 + 1] = w1;
}

// ---- aggregation: ONE NODE PER LANE, 16 f32 register accumulators, zero LDS ----
template <int LAYER>
__global__ void __launch_bounds__(256)
k_aggn(const uint2* __restrict__ payload, const int* __restrict__ rs,
       const uint4* __restrict__ hb, const float* __restrict__ dis,
       const float* __restrict__ b1, uint4* __restrict__ hb2,
       float* __restrict__ g, int N) {
  int n = blockIdx.x * 256 + threadIdx.x;
  if (n >= N) return;
  int e0 = rs[n], e1 = rs[n + 1];
  float a0 = 0, a1 = 0, a2 = 0, a3 = 0, a4 = 0, a5 = 0, a6 = 0, a7 = 0;
  float a8 = 0, a9 = 0, a10 = 0, a11 = 0, a12 = 0, a13 = 0, a14 = 0, a15 = 0;
#pragma unroll 2
  for (int e = e0; e < e1; ++e) {
    uint2 p = payload[e];
    const uint4* row = hb + ((size_t)p.x * 2);
    uint4 r0 = row[0];
    uint4 r1 = row[1];
    float w = __uint_as_float(p.y);
    a0  = fmaf(blo(r0.x), w, a0);  a1  = fmaf(bhi(r0.x), w, a1);
    a2  = fmaf(blo(r0.y), w, a2);  a3  = fmaf(bhi(r0.y), w, a3);
    a4  = fmaf(blo(r0.z), w, a4);  a5  = fmaf(bhi(r0.z), w, a5);
    a6  = fmaf(blo(r0.w), w, a6);  a7  = fmaf(bhi(r0.w), w, a7);
    a8  = fmaf(blo(r1.x), w, a8);  a9  = fmaf(bhi(r1.x), w, a9);
    a10 = fmaf(blo(r1.y), w, a10); a11 = fmaf(bhi(r1.y), w, a11);
    a12 = fmaf(blo(r1.z), w, a12); a13 = fmaf(bhi(r1.z), w, a13);
    a14 = fmaf(blo(r1.w), w, a14); a15 = fmaf(bhi(r1.w), w, a15);
  }
  uint4 s0 = hb[(size_t)n * 2];
  uint4 s1 = hb[(size_t)n * 2 + 1];
  float di = dis[n];
  a0  = (a0  + blo(s0.x)) * di;  a1  = (a1  + bhi(s0.x)) * di;
  a2  = (a2  + blo(s0.y)) * di;  a3  = (a3  + bhi(s0.y)) * di;
  a4  = (a4  + blo(s0.z)) * di;  a5  = (a5  + bhi(s0.z)) * di;
  a6  = (a6  + blo(s0.w)) * di;  a7  = (a7  + bhi(s0.w)) * di;
  a8  = (a8  + blo(s1.x)) * di;  a9  = (a9  + bhi(s1.x)) * di;
  a10 = (a10 + blo(s1.y)) * di;  a11 = (a11 + bhi(s1.y)) * di;
  a12 = (a12 + blo(s1.z)) * di;  a13 = (a13 + bhi(s1.z)) * di;
  a14 = (a14 + blo(s1.w)) * di;  a15 = (a15 + bhi(s1.w)) * di;
  if (LAYER == 1) {
    a0  = fmaxf(a0  + b1[0],  0.0f) * di;  a1  = fmaxf(a1  + b1[1],  0.0f) * di;
    a2  = fmaxf(a2  + b1[2],  0.0f) * di;  a3  = fmaxf(a3  + b1[3],  0.0f) * di;
    a4  = fmaxf(a4  + b1[4],  0.0f) * di;  a5  = fmaxf(a5  + b1[5],  0.0f) * di;
    a6  = fmaxf(a6  + b1[6],  0.0f) * di;  a7  = fmaxf(a7  + b1[7],  0.0f) * di;
    a8  = fmaxf(a8  + b1[8],  0.0f) * di;  a9  = fmaxf(a9  + b1[9],  0.0f) * di;
    a10 = fmaxf(a10 + b1[10], 0.0f) * di;  a11 = fmaxf(a11 + b1[11], 0.0f) * di;
    a12 = fmaxf(a12 + b1[12], 0.0f) * di;  a13 = fmaxf(a13 + b1[13], 0.0f) * di;
    a14 = fmaxf(a14 + b1[14], 0.0f) * di;  a15 = fmaxf(a15 + b1[15], 0.0f) * di;
    uint4 w0, w1;
    w0.x = pack2(a0,  a1);  w0.y = pack2(a2,  a3);
    w0.z = pack2(a4,  a5);  w0.w = pack2(a6,  a7);
    w1.x = pack2(a8,  a9);  w1.y = pack2(a10, a11);
    w1.z = pack2(a12, a13); w1.w = pack2(a14, a15);
    hb2[(size_t)n * 2]     = w0;
    hb2[(size_t)n * 2 + 1] = w1;
  } else {
    float4* gr = reinterpret_cast<float4*>(g + (size_t)n * HID);
    gr[0] = make_float4(a0,  a1,  a2,  a3);
    gr[1] = make_float4(a4,  a5,  a6,  a7);
    gr[2] = make_float4(a8,  a9,  a10, a11);
    gr[3] = make_float4(a12, a13, a14, a15);
  }
}

// ---- out = log_softmax(g @ W2 + b2), thread-per-node ----
__global__ void k_out(const float* __restrict__ g, const float* __restrict__ W2,
                      const float* __restrict__ b2, float* __restrict__ out, int N) {
  int n = blockIdx.x * blockDim.x + threadIdx.x;
  if (n >= N) return;
  float gv[HID];
#pragma unroll
  for (int j = 0; j < HID; ++j) gv[j] = g[(size_t)n * HID + j];
  float o[NCLS];
#pragma unroll
  for (int c = 0; c < NCLS; ++c) o[c] = b2[c];
#pragma unroll
  for (int j = 0; j < HID; ++j) {
    float gj = gv[j];
    const float* wr = W2 + (size_t)j * NCLS;
#pragma unroll
    for (int c = 0; c < NCLS; ++c) o[c] = fmaf(gj, wr[c], o[c]);
  }
  float m = o[0];
#pragma unroll
  for (int c = 1; c < NCLS; ++c) m = fmaxf(m, o[c]);
  float ss = 0.0f;
#pragma unroll
  for (int c = 0; c < NCLS; ++c) ss += expf(o[c] - m);
  float lse = m + logf(ss);
  float* orow = out + (size_t)n * NCLS;
#pragma unroll
  for (int c = 0; c < NCLS; ++c) orow[c] = o[c] - lse;
}

extern "C" void kernel_launch(void* const* d_in, const int* in_sizes, int n_in,
                              void* d_out, int out_size, void* d_ws, size_t ws_size,
                              hipStream_t stream) {
  const float* x  = (const float*)d_in[0];
  const int*   ei = (const int*)d_in[1];
  const float* ew = (const float*)d_in[2];
  const float* W1 = (const float*)d_in[3];
  const float* b1 = (const float*)d_in[4];
  const float* W2 = (const float*)d_in[5];
  const float* b2 = (const float*)d_in[6];
  float* out = (float*)d_out;

  const int N = in_sizes[0] / F_IN;   // 100000
  const int E = in_sizes[2];          // 3200000
  const int* src = ei;
  const int* dst = ei + E;

  const int NB   = (N + 127) >> 7;             // 782 buckets
  const int NBLK = (E + CHUNK - 1) / CHUNK;    // 782 chunks
  const long long SCT = (long long)NB * NBLK + 1;
  const int Npad = (int)((SCT + 1023) & ~1023LL);
  const int nbScan = Npad / 1024;
  const int Nr   = (NB * 128 + 256 + 255) & ~255;
  const size_t SEGSZ = (size_t)NBLK * (NB + 1) + 4;

  // ws layout (4B words): counts[Npad] | bsum[1024] | dis[Nr] | rs[Nr] |
  //   hb1[N*8] | hb2[N*8] | g[N*16] | payloadA[2E] | segs[SEGSZ] | payloadB[2E] | xtb[NP*256]
  int* counts = (int*)d_ws;
  int* bsum   = counts + Npad;
  float* dis  = (float*)(bsum + 1024);
  int* rs     = (int*)(dis + Nr);
  uint4* hb1  = (uint4*)(rs + Nr);
  uint4* hb2  = hb1 + (size_t)N * 2;
  float* g    = (float*)(hb2 + (size_t)N * 2);
  uint2* payloadA = (uint2*)(g + (size_t)N * HID);
  int* segs   = (int*)(payloadA + (size_t)E);
  uint2* payloadB = (uint2*)(segs + SEGSZ);
  unsigned* xtb32 = (unsigned*)(payloadB + (size_t)E);
  size_t need = ((char*)(xtb32 + (size_t)NP * F_IN / 2)) - (char*)d_ws;
  bool fast = (ws_size >= need);

  const int padLo = NB * NBLK;
  k_zpad<<<(Npad - padLo + 255) / 256, 256, 0, stream>>>(counts, padLo, Npad);
  k_count<<<NBLK, 256, 0, stream>>>(dst, counts, E, NB, NBLK);
  k_scanA<<<nbScan, 256, 0, stream>>>(counts, bsum);
  k_scanB<<<1, 1024, 0, stream>>>(bsum, nbScan);
  k_scanC<<<nbScan, 256, 0, stream>>>(counts, bsum);
  k_scat2<<<NBLK, 256, 0, stream>>>(src, dst, ew, payloadA, segs, E, NB);
  k_sortb2<<<NB, 256, 0, stream>>>(payloadA, segs, counts, payloadB, rs, dis, N, NB, NBLK);
  if (fast) {
    k_xpose<<<(NP / 128) * 8, 256, 0, stream>>>(x, xtb32, N);
    k_gemm1b<<<NP / 128, 256, 0, stream>>>(xtb32, W1, dis, hb1, N);
  } else {
    k_gemm1<<<(N + 255) / 256, 256, 0, stream>>>(x, W1, dis, hb1, N);
  }
  k_aggn<1><<<(N + 255) / 256, 256, 0, stream>>>(payloadB, rs, hb1, dis, b1, hb2, nullptr, N);
  k_aggn<2><<<(N + 255) / 256, 256, 0, stream>>>(payloadB, rs, hb2, dis, nullptr, nullptr, g, N);
  k_out<<<(N + 255) / 256, 256, 0, stream>>>(g, W2, b2, out, N);
}